// Round 1
// baseline (255.999 us; speedup 1.0000x reference)
//
#include <hip/hip_runtime.h>
#include <math.h>

// Problem constants (fixed by the reference):
//   N=8, C1=C2=512, H=W=64, HEADS=8  ->  HW=4096, head dim D=64
#define NB      8
#define CCH     512
#define NHEADS  8
#define DH      64
#define HW      4096
#define TEN     (NB*CCH*HW)          // 16,777,216 elements per tensor (67.1 MB fp32)

// ---------------------------------------------------------------------------
// Kernel 1: per-(n,head,branch) context matrix
//   ctx[k][v] = sum_p softmax_p(K)[k,p] * V[v,p]
// K,V are 1x1-conv projections computed on the fly (fused), softmax over the
// 4096 spatial positions is done ONLINE (flash-style running max/sum), so no
// K/Q/V tensors are ever materialized. Branch 0: K=k1(x_l), V=v2(x_g) (feeds
// out_g); branch 1: K=k2(x_g), V=v1(x_l) (feeds out_l).
// When resweight==0 the attention contributes exactly 0 -> early return.
// ---------------------------------------------------------------------------
__global__ __launch_bounds__(256)
void eff_attn_ctx_kernel(const float* __restrict__ x_l, const float* __restrict__ x_g,
                         const float* __restrict__ k1_w, const float* __restrict__ k1_b,
                         const float* __restrict__ v1_w, const float* __restrict__ v1_b,
                         const float* __restrict__ k2_w, const float* __restrict__ k2_b,
                         const float* __restrict__ v2_w, const float* __restrict__ v2_b,
                         const float* __restrict__ resweight,
                         float* __restrict__ ctx_out)   // [2][64][64][64]
{
    if (resweight[0] == 0.0f) return;   // agg*0 == 0 exactly for finite agg

    const int branch = blockIdx.y;
    const float *xK, *wK, *bK, *xV, *wV, *bV;
    if (branch == 0) { xK = x_l; wK = k1_w; bK = k1_b; xV = x_g; wV = v2_w; bV = v2_b; }
    else             { xK = x_g; wK = k2_w; bK = k2_b; xV = x_l; wV = v1_w; bV = v1_b; }

    const int nh = blockIdx.x;          // 0..63
    const int n  = nh >> 3, h = nh & 7;
    const int t  = threadIdx.x;
    const int krow = t >> 2;            // row this thread owns (k for K, v for V)
    const int jg   = t & 3;             // 16-wide column group

    __shared__ float xt[64][65];        // staged input tile (c x p), +1 pad
    __shared__ float Kt[64][65];        // K tile (k x p) -> exp(K-m) in place
    __shared__ float Vt[64][65];        // V tile (v x p)
    __shared__ float m_s[64], s_s[64], f_s[64];

    if (t < 64) { m_s[t] = -INFINITY; s_s[t] = 0.0f; }

    float ctx_reg[16];                  // this thread: ctx[krow][jg*16 .. +15]
    #pragma unroll
    for (int e = 0; e < 16; ++e) ctx_reg[e] = 0.0f;

    const float bk = bK[h*DH + krow];
    const float bv = bV[h*DH + krow];

    for (int p0 = 0; p0 < HW; p0 += 64) {
        float acc[16];
        // ----- K projection: Kt[k][j] = bK + sum_c wK[k,c] * xK[n,c,p0+j]
        #pragma unroll
        for (int jj = 0; jj < 16; ++jj) acc[jj] = bk;
        for (int c0 = 0; c0 < CCH; c0 += 64) {
            __syncthreads();
            #pragma unroll
            for (int r = 0; r < 16; ++r) {
                int e = r*256 + t;
                int i = e >> 6, j = e & 63;
                xt[i][j] = xK[((size_t)(n*CCH + c0 + i))*HW + p0 + j];
            }
            __syncthreads();
            const float* wrow = &wK[(size_t)(h*DH + krow)*CCH + c0];
            for (int i = 0; i < 64; ++i) {
                float w = wrow[i];
                #pragma unroll
                for (int jj = 0; jj < 16; ++jj) acc[jj] += w * xt[i][jg*16 + jj];
            }
        }
        #pragma unroll
        for (int jj = 0; jj < 16; ++jj) Kt[krow][jg*16 + jj] = acc[jj];
        // ----- V projection
        #pragma unroll
        for (int jj = 0; jj < 16; ++jj) acc[jj] = bv;
        for (int c0 = 0; c0 < CCH; c0 += 64) {
            __syncthreads();
            #pragma unroll
            for (int r = 0; r < 16; ++r) {
                int e = r*256 + t;
                int i = e >> 6, j = e & 63;
                xt[i][j] = xV[((size_t)(n*CCH + c0 + i))*HW + p0 + j];
            }
            __syncthreads();
            const float* wrow = &wV[(size_t)(h*DH + krow)*CCH + c0];
            for (int i = 0; i < 64; ++i) {
                float w = wrow[i];
                #pragma unroll
                for (int jj = 0; jj < 16; ++jj) acc[jj] += w * xt[i][jg*16 + jj];
            }
        }
        #pragma unroll
        for (int jj = 0; jj < 16; ++jj) Vt[krow][jg*16 + jj] = acc[jj];
        __syncthreads();
        // ----- online softmax update for each K row over this p-tile
        if (t < 64) {
            float m老 = m_s[t];
            float tmax = -INFINITY;
            for (int j = 0; j < 64; ++j) tmax = fmaxf(tmax, Kt[t][j]);
            float mnew = fmaxf(m老, tmax);
            float f = __expf(m老 - mnew);           // 0 on first tile (m=-inf)
            float sum = 0.0f;
            for (int j = 0; j < 64; ++j) {
                float e = __expf(Kt[t][j] - mnew);
                Kt[t][j] = e;
                sum += e;
            }
            s_s[t] = s_s[t]*f + sum;
            m_s[t] = mnew;
            f_s[t] = f;
        }
        __syncthreads();
        // ----- ctx accumulate: ctx[k][v] = ctx[k][v]*f + sum_j expK[k][j]*V[v][j]
        {
            const float f = f_s[krow];
            #pragma unroll
            for (int e = 0; e < 16; ++e) ctx_reg[e] *= f;
            for (int j = 0; j < 64; ++j) {
                float pk = Kt[krow][j];
                #pragma unroll
                for (int e = 0; e < 16; ++e) ctx_reg[e] += pk * Vt[jg*16 + e][j];
            }
        }
        __syncthreads();
    }

    // normalize by softmax denominator and write out
    const float inv_s = 1.0f / s_s[krow];
    #pragma unroll
    for (int e = 0; e < 16; ++e)
        ctx_out[((size_t)(branch*64 + nh)*DH + krow)*DH + jg*16 + e] = ctx_reg[e] * inv_s;
}

// ---------------------------------------------------------------------------
// Kernel 2: output.  Branch 0: out_g = x_g + rw * (ctx2^T . softmax_ch(Q1)),
// branch 1: out_l = x_l + rw * (ctx1^T . softmax_ch(Q2)).  Q projection fused.
// When rw == 0 this is exactly out = x (bitwise) -> pure vectorized copy.
// Grid: (64 nh * 32 p-chunks, 2 branches) x 256 threads.
// ---------------------------------------------------------------------------
__global__ __launch_bounds__(256)
void eff_attn_out_kernel(const float* __restrict__ x_l, const float* __restrict__ x_g,
                         const float* __restrict__ q1_w, const float* __restrict__ q1_b,
                         const float* __restrict__ q2_w, const float* __restrict__ q2_b,
                         const float* __restrict__ resweight,
                         const float* __restrict__ ctx_in,
                         float* __restrict__ out)       // [out_l | out_g]
{
    const int branch = blockIdx.y;            // 0 -> out_g, 1 -> out_l
    const float rw = resweight[0];
    const int nh = blockIdx.x >> 5;           // 0..63
    const int pc = blockIdx.x & 31;           // 32 chunks of 128 positions
    const int n  = nh >> 3, h = nh & 7;
    const int p0 = pc * 128;
    const int t  = threadIdx.x;

    const float* xr = (branch == 0) ? x_g : x_l;            // residual source
    float*       o  = out + ((branch == 0) ? (size_t)TEN : (size_t)0);

    if (rw == 0.0f) {
        // out = x exactly; copy this block's 64ch x 128p slice with float4.
        #pragma unroll
        for (int r = 0; r < 8; ++r) {
            int idx = r*256 + t;              // 0..2047 float4s
            int c  = idx >> 5;                // channel within head block
            int jo = idx & 31;                // float4 within the 128-p row
            size_t off = ((size_t)(n*CCH + h*DH + c))*HW + p0 + jo*4;
            *(float4*)(o + off) = *(const float4*)(xr + off);
        }
        return;
    }

    const float* xq = (branch == 0) ? x_l : x_g;
    const float* wQ = (branch == 0) ? q1_w : q2_w;
    const float* bQ = (branch == 0) ? q1_b : q2_b;

    __shared__ float ctxs[64][65];            // ctx[k][v]
    __shared__ float xt[64][65];
    __shared__ float Qt[64][65];              // Q tile (k x p) -> softmaxed

    #pragma unroll
    for (int r = 0; r < 16; ++r) {
        int e = r*256 + t;
        ctxs[e >> 6][e & 63] =
            ctx_in[((size_t)(branch*64 + nh)*DH + (e >> 6))*DH + (e & 63)];
    }

    const int krow = t >> 2, jg = t & 3;
    const float bq = bQ[h*DH + krow];

    for (int sub = 0; sub < 2; ++sub) {
        const int ps = p0 + sub*64;
        float acc[16];
        #pragma unroll
        for (int jj = 0; jj < 16; ++jj) acc[jj] = bq;
        for (int c0 = 0; c0 < CCH; c0 += 64) {
            __syncthreads();
            #pragma unroll
            for (int r = 0; r < 16; ++r) {
                int e = r*256 + t;
                int i = e >> 6, j = e & 63;
                xt[i][j] = xq[((size_t)(n*CCH + c0 + i))*HW + ps + j];
            }
            __syncthreads();
            const float* wrow = &wQ[(size_t)(h*DH + krow)*CCH + c0];
            for (int i = 0; i < 64; ++i) {
                float w = wrow[i];
                #pragma unroll
                for (int jj = 0; jj < 16; ++jj) acc[jj] += w * xt[i][jg*16 + jj];
            }
        }
        #pragma unroll
        for (int jj = 0; jj < 16; ++jj) Qt[krow][jg*16 + jj] = acc[jj];
        __syncthreads();
        // channel softmax: each of 64 threads owns column j and reduces over k
        if (t < 64) {
            float mx = -INFINITY;
            for (int k = 0; k < 64; ++k) mx = fmaxf(mx, Qt[k][t]);
            float sum = 0.0f;
            for (int k = 0; k < 64; ++k) {
                float e = __expf(Qt[k][t] - mx);
                Qt[k][t] = e;
                sum += e;
            }
            float inv = 1.0f / sum;
            for (int k = 0; k < 64; ++k) Qt[k][t] *= inv;
        }
        __syncthreads();
        // out[v][j] = sum_k ctx[k][v] * q[k][j];  fused residual + rw scale
        #pragma unroll
        for (int jj = 0; jj < 16; ++jj) {
            int j = jg*16 + jj;
            float s = 0.0f;
            for (int k = 0; k < 64; ++k) s += ctxs[k][krow] * Qt[k][j];
            size_t off = ((size_t)(n*CCH + h*DH + krow))*HW + ps + j;
            o[off] = xr[off] + rw * s;
        }
        __syncthreads();
    }
}

extern "C" void kernel_launch(void* const* d_in, const int* in_sizes, int n_in,
                              void* d_out, int out_size, void* d_ws, size_t ws_size,
                              hipStream_t stream) {
    const float* x_l  = (const float*)d_in[0];
    const float* x_g  = (const float*)d_in[1];
    const float* k1_w = (const float*)d_in[2];
    const float* k1_b = (const float*)d_in[3];
    const float* q1_w = (const float*)d_in[4];
    const float* q1_b = (const float*)d_in[5];
    const float* v1_w = (const float*)d_in[6];
    const float* v1_b = (const float*)d_in[7];
    const float* k2_w = (const float*)d_in[8];
    const float* k2_b = (const float*)d_in[9];
    const float* q2_w = (const float*)d_in[10];
    const float* q2_b = (const float*)d_in[11];
    const float* v2_w = (const float*)d_in[12];
    const float* v2_b = (const float*)d_in[13];
    const float* resw = (const float*)d_in[14];

    float* ctx = (float*)d_ws;    // 2*64*64*64 floats = 2 MiB scratch
    float* out = (float*)d_out;   // [out_l (TEN) | out_g (TEN)]

    eff_attn_ctx_kernel<<<dim3(64, 2), 256, 0, stream>>>(
        x_l, x_g, k1_w, k1_b, v1_w, v1_b, k2_w, k2_b, v2_w, v2_b, resw, ctx);

    eff_attn_out_kernel<<<dim3(2048, 2), 256, 0, stream>>>(
        x_l, x_g, q1_w, q1_b, q2_w, q2_b, resw, ctx, out);
}